// Round 7
// baseline (512.255 us; speedup 1.0000x reference)
//
#include <hip/hip_runtime.h>
#include <hip/hip_bf16.h>

typedef __attribute__((ext_vector_type(8))) short short8;
typedef __attribute__((ext_vector_type(16))) float f32x16;

// ---------------- workspace layout (bytes) ----------------
// Xpad bf16 NHWC [32][58][58][256]                    : 55,115,776 B
// Wq   bf16 32x32-frag layout [4][2][9][8][...]       :  4,718,592 B
// pooled f32 [32][256] (SUMS, zeroed by quant blk 0)  :     32,768 B
// idx  int [32]                                       :        128 B
#define XPAD_OFF   0u
#define WQ_OFF     55115776u
#define POOL_OFF   59834368u
#define IDX_OFF    59867136u

__device__ __forceinline__ void gl_lds16(const void* g, void* l) {
  __builtin_amdgcn_global_load_lds(
      (const __attribute__((address_space(1))) unsigned int*)g,
      (__attribute__((address_space(3))) unsigned int*)l, 16, 0, 0);
}

// ---- 1. fc1/relu/fc2 + argmax: one block per sample ----
__global__ __launch_bounds__(128) void fc_argmax_kernel(
    const float* __restrict__ pooled, const float* __restrict__ w_fc1,
    const float* __restrict__ w_fc2, const float* __restrict__ b_fc2,
    float* __restrict__ raw_out, int* __restrict__ idx) {
  __shared__ float h[65];
  __shared__ float raws[4];
  const int b = blockIdx.x, t = threadIdx.x;
  if (t < 65) {
    float s = 0.f;
    const float4* pb = (const float4*)(pooled + b * 256);
    const float4* wr = (const float4*)(w_fc1 + t * 256);
    for (int c = 0; c < 64; ++c) {
      const float4 a4 = pb[c], b4 = wr[c];
      s += a4.x * b4.x + a4.y * b4.y + a4.z * b4.z + a4.w * b4.w;
    }
    s *= (1.0f / 3136.0f);
    h[t] = s > 0.f ? s : 0.f;
  }
  __syncthreads();
  if (t < 4) {
    float s = b_fc2[t];
    const float* wr = w_fc2 + t * 65;
    for (int j = 0; j < 65; ++j) s += h[j] * wr[j];
    raws[t] = s;
    raw_out[b * 4 + t] = s;
  }
  __syncthreads();
  if (t == 0) {
    int best = 0; float bv = raws[0];
    for (int k = 1; k < 4; ++k) if (raws[k] > bv) { bv = raws[k]; best = k; }
    idx[b] = best;
  }
}

// ---- 2. LSQ quantize + reorder, coalesced via LDS transpose ----
// (verified round 4; ~6-8us) 256 blocks, each owns (k, oc-tile 32, ch-tile 32,
// all 9 taps); coalesced float4 stage -> LDS [32][292] -> native-order short8
// stores. Output mapping matches conv's W0 indexing:
//   u = ((k*2+ot)*9+tap)*64 + cbh*8+wm*4+octile*2+s ; elem d = u*512+lane*8+cl
//   oc = ot*128+wm*64+octile*32+(lane&31), ch = cbh*32+s*16+(lane>>5)*8+cl.
// Block 0 also zeroes pooled (replaces the memset dispatch; quant runs first).
__global__ __launch_bounds__(256) void quant_kernel(
    const float* __restrict__ weight, const float* __restrict__ alpha,
    __hip_bfloat16* __restrict__ Wq, float* __restrict__ pooled) {
  __shared__ __attribute__((aligned(16))) float Ws[32 * 292];
  const int tid = threadIdx.x;
  const int B = blockIdx.x;
  if (B == 0) {
    for (int i = tid; i < 8192; i += 256) pooled[i] = 0.f;
  }
  const int cbh    = B & 7;
  const int octile = (B >> 3) & 1;
  const int wm     = (B >> 4) & 1;
  const int ot     = (B >> 5) & 1;
  const int k      = B >> 6;
  const int oc0 = ot * 128 + wm * 64 + octile * 32;

  // stage: oc row (tid>>3), quad (tid&7); 9 float4 per thread
  const int ocr = tid >> 3, q = tid & 7;
  const float4* src = (const float4*)weight +
                      (size_t)k * 147456 + (size_t)(oc0 + ocr) * 576 + cbh * 72;
  #pragma unroll
  for (int j = 0; j < 9; ++j) {
    const float4 v = src[q + 8 * j];
    *(float4*)&Ws[ocr * 292 + 4 * (q + 8 * j)] = v;
  }
  __syncthreads();

  // write: thread t = (p = t>>7 tap parity, s = (t>>6)&1, lane = t&63)
  const int p    = tid >> 7;
  const int s    = (tid >> 6) & 1;
  const int lane = tid & 63;
  const int ocl  = lane & 31;
  const int khl  = lane >> 5;
  const float a = alpha[k];
  const int ubase = ((k * 2 + ot) * 9) * 64 + (cbh * 8 + wm * 4 + octile * 2 + s);
  #pragma unroll
  for (int m = 0; m < 5; ++m) {
    const int tap = 2 * m + p;
    if (tap > 8) break;   // only (m=4, p=1)
    union { short8 v; __hip_bfloat16 e[8]; } uo;
    #pragma unroll
    for (int cl = 0; cl < 8; ++cl) {
      const int chl = s * 16 + khl * 8 + cl;
      float v = Ws[ocl * 292 + chl * 9 + tap] / a;
      if (oc0 == 0 && ocl == 0 && cbh == 0 && chl == 0 && tap == 0) {
        if (k == 0)      v = fminf(fmaxf(v, -2.f), 1.f);
        else if (k == 1) v = fminf(fmaxf(v, -4.f), 3.f);
        else if (k == 2) v = fminf(fmaxf(v, -8.f), 7.f);
      }
      uo.e[cl] = __float2bfloat16(rintf(v) * a);
    }
    const size_t u = (size_t)(ubase + tap * 64);
    *(short8*)&Wq[u * 512 + lane * 8] = uo.v;
  }
}

// ---- 3. pad + NCHW->NHWC + bf16, v3 (verified round 5) ----
// One block per (y-row-pair, b): grid (29, 32), 512 threads. Thread t owns
// (row slot r = t>>8, channel c = t&255): loads its full 56-px row as 14
// contiguous float4, pools in registers, converts to bf16 into LDS transpose
// buffer [2][56][264]; store phase emits full 512B channel rows including
// zero pad columns (x'=0,57) and zero border rows (y'=0,57).
__global__ __launch_bounds__(512) void padx_kernel(const float* __restrict__ x,
                                                   __hip_bfloat16* __restrict__ Xpad,
                                                   float* __restrict__ pooled) {
  __shared__ __attribute__((aligned(16))) __hip_bfloat16 T2[2][56][264];
  const int q = blockIdx.x;        // 0..28 -> y' rows {2q, 2q+1}
  const int b = blockIdx.y;        // 0..31
  const int tid = threadIdx.x;
  const int r = tid >> 8;          // wave-uniform row slot (waves 0-3 / 4-7)
  const int c = tid & 255;
  const int yp  = 2 * q + r;       // 0..57
  const int yin = yp - 1;          // input row, valid in [0,56)
  if (yin >= 0 && yin < 56) {
    const float4* src = (const float4*)(x + ((size_t)(b * 256 + c) * 3136 + yin * 56));
    float4 v[14];
    #pragma unroll
    for (int i = 0; i < 14; ++i) v[i] = src[i];
    float s = 0.f;
    #pragma unroll
    for (int i = 0; i < 14; ++i) {
      s += v[i].x + v[i].y + v[i].z + v[i].w;
      T2[r][4 * i + 0][c] = __float2bfloat16(v[i].x);
      T2[r][4 * i + 1][c] = __float2bfloat16(v[i].y);
      T2[r][4 * i + 2][c] = __float2bfloat16(v[i].z);
      T2[r][4 * i + 3][c] = __float2bfloat16(v[i].w);
    }
    atomicAdd(pooled + b * 256 + c, s);
  }
  __syncthreads();
  // write out 2 rows x 58 px x 256 ch bf16; granule = 16B (8 ch).
  const short8 zero8 = (short8){0, 0, 0, 0, 0, 0, 0, 0};
  for (int i = tid; i < 3712; i += 512) {      // 2*58*32 granules
    const int cg  = i & 31;
    const int px  = (i >> 5) % 58;
    const int rr  = i / (58 * 32);
    const int ypo = 2 * q + rr;
    const int yio = ypo - 1;
    short8 v;
    if (yio < 0 || yio >= 56 || px == 0 || px == 57) v = zero8;
    else v = *(const short8*)&T2[rr][px - 1][cg * 8];
    *(short8*)(Xpad + (((size_t)(b * 58 + ypo) * 58 + px) * 256 + cg * 8)) = v;
  }
}

// ---- 4. conv as implicit GEMM, bf16 MFMA 32x32x16 ----
// v8 = v4 EXACTLY (verified 126.0us, MfmaUtil 45%, FETCH 64.5MB) + T5
// s_setprio(1/0) around each tap's compute cluster. v4 design: 256-thr
// 4-wave block 128oc x 256px (wave tile 64oc x 128px, acc[2][4]=128 AGPR),
// XCD grid remap (b, pt*2+ot) -> linear%8=b%8 pins sample to one XCD (L2
// reuse of X tile + ot-pair sharing); X double-buffered LDS, staging spread
// taps 0..5; W depth-2 register ring (3 banks, t+2 prefetch, 4 granules).
// T5 rationale: waves sync only per chunk (not per tap) and 2 independent
// blocks/CU -> staging-phase vs compute-phase role diversity for the CU
// scheduler to arbitrate (catalog: null on lockstep m190, + on role-split).
// POST-MORTEM LOG (do not retry):
//  - launch_bounds(256,3): VGPR cap 170 < 128acc+~100 -> spill, 8.7x slower.
//  - wave retile 128oc x 64px (v2 512-thr, v7 256-thr): BOTH ~35% slower.
//    8 W-loads/wave/tap + t+1 ring outweighs halved LDS reads/conflicts.
//    LDS is NOT the critical path; latency-hiding capacity at 2 wv/SIMD is.
__global__ __launch_bounds__(256, 2) void conv_kernel(
    const __hip_bfloat16* __restrict__ Xpad, const __hip_bfloat16* __restrict__ Wq,
    const int* __restrict__ idx, const float* __restrict__ bias_w,
    float* __restrict__ out) {
  // per buffer: 6 rows x 58 px x 4 granules = 1392 data granules; padded to
  // 1424 granules (22784 B) to absorb discarded-lane reads (col<=65) and the
  // staging tail. 2 buffers = 45568 B.
  __shared__ __attribute__((aligned(16))) __hip_bfloat16 Xs[22784];

  const int tid = threadIdx.x;
  const int lane = tid & 63;
  const int w = tid >> 6;
  const int wm = w & 1;          // oc-half (64)
  const int wn = w >> 1;         // px-half: rows {0,1} vs {2,3}

  const int b  = blockIdx.x;          // 0..31 -> XCD b%8
  const int pt = blockIdx.y >> 1;     // 0..13 -> output rows 4*pt..4*pt+3
  const int ot = blockIdx.y & 1;      // 0..1 (adjacent dispatch with its pair)
  const int Y0 = pt * 4;
  const int OC0 = ot * 128;
  const int kb = idx[b];

  const __hip_bfloat16* xb = Xpad + (size_t)b * (58 * 58 * 256);
  const short8* W0 = (const short8*)Wq + (size_t)(kb * 2 + ot) * 36864;

  f32x16 acc[2][4];
  #pragma unroll
  for (int i = 0; i < 2; ++i)
    #pragma unroll
    for (int j = 0; j < 4; ++j)
      acc[i][j] = (f32x16){0,0,0,0,0,0,0,0,0,0,0,0,0,0,0,0};

  const int nlo = lane & 31;     // oc%32 (A) / px col (B)
  const int khalf = lane >> 5;   // ch-half selector

  // one staging segment (64 granules) of chunk cbn into buffer bufsel
  auto stageseg = [&](int cbn, int bufsel, int k) {
    int sidx = k * 64 + lane;
    int p = sidx >> 2;
    if (p > 347) p = 347;                   // tail dups -> pad granules
    const int gsel = (sidx & 3) ^ ((p >> 1) & 3);
    const int r = p / 58, xc = p - r * 58;
    gl_lds16(xb + (((Y0 + r) * 58 + xc) * 256 + cbn * 32 + gsel * 8),
             (char*)Xs + bufsel * 22784 + k * 1024);
  };

  for (int k = w; k < 22; k += 4) stageseg(0, 0, k);   // chunk 0 burst
  __syncthreads();

  // W register ring, depth 2: afr[set][octile*2+s]
  short8 afr[3][4];
  #pragma unroll
  for (int oc2 = 0; oc2 < 2; ++oc2)
    #pragma unroll
    for (int s2 = 0; s2 < 2; ++s2) {
      afr[0][oc2 * 2 + s2] = W0[0 * 4096 + 0 * 512 + wm * 256 + oc2 * 128 + s2 * 64 + lane];
      afr[1][oc2 * 2 + s2] = W0[1 * 4096 + 0 * 512 + wm * 256 + oc2 * 128 + s2 * 64 + lane];
    }

  for (int cbh = 0; cbh < 8; ++cbh) {
    const __hip_bfloat16* cur = Xs + (cbh & 1) * 11392;
    const int nb = (cbh + 1) & 1;

    #pragma unroll
    for (int t = 0; t < 9; ++t) {
      const int dy = t / 3, dx = t - dy * 3;
      // spread X staging for next chunk: ~3-4 segs per tap, taps 0..5
      if (cbh < 7) {
        if (t < 5) stageseg(cbh + 1, nb, w + 4 * t);
        else if (t == 5 && w < 2) stageseg(cbh + 1, nb, w + 20);
      }
      // W prefetch for tt+2 (depth-2 ring)
      if (cbh < 7 || t < 7) {
        const int tap2 = (t + 2) % 9, cb2 = cbh + (t + 2) / 9;
        #pragma unroll
        for (int oc2 = 0; oc2 < 2; ++oc2)
          #pragma unroll
          for (int s2 = 0; s2 < 2; ++s2)
            afr[(t + 2) % 3][oc2 * 2 + s2] =
                W0[tap2 * 4096 + cb2 * 512 + wm * 256 + oc2 * 128 + s2 * 64 + lane];
      }
      // compute: 2 K16-steps x 4 px-tiles x 2 oc-tiles (T5: raise wave prio
      // while issuing the ds_read+MFMA cluster)
      __builtin_amdgcn_s_setprio(1);
      #pragma unroll
      for (int s = 0; s < 2; ++s) {
        #pragma unroll
        for (int j = 0; j < 4; ++j) {
          const int row = wn * 2 + (j >> 1) + dy;
          const int col = (j & 1) * 32 + nlo + dx;
          const int p = row * 58 + col;
          const int slot = p * 4 + ((s * 2 + khalf) ^ ((p >> 1) & 3));
          const short8 bfr = *(const short8*)&cur[slot * 8];
          #pragma unroll
          for (int i = 0; i < 2; ++i)
            acc[i][j] = __builtin_amdgcn_mfma_f32_32x32x16_bf16(
                afr[t % 3][i * 2 + s], bfr, acc[i][j], 0, 0, 0);
        }
      }
      __builtin_amdgcn_s_setprio(0);
    }
    __syncthreads();   // staging of next chunk complete; cur readers done
  }

  // epilogue: 32x32 C/D: col=lane&31, row=(reg&3)+8*(reg>>2)+4*(lane>>5)
  const float* biasb = bias_w + kb * 256;
  #pragma unroll
  for (int i = 0; i < 2; ++i) {
    #pragma unroll
    for (int j = 0; j < 4; ++j) {
      const int xcol = (j & 1) * 32 + nlo;
      if (xcol < 56) {
        const int y = Y0 + wn * 2 + (j >> 1);
        #pragma unroll
        for (int reg = 0; reg < 16; ++reg) {
          const int row = (reg & 3) + 8 * (reg >> 2) + 4 * khalf;
          const int oc = OC0 + wm * 64 + i * 32 + row;
          out[(((size_t)b * 256 + oc) * 56 + y) * 56 + xcol] =
              acc[i][j][reg] + biasb[oc];
        }
      }
    }
  }
}

extern "C" void kernel_launch(void* const* d_in, const int* in_sizes, int n_in,
                              void* d_out, int out_size, void* d_ws, size_t ws_size,
                              hipStream_t stream) {
  const float* x      = (const float*)d_in[0];
  const float* w_fc1  = (const float*)d_in[1];
  const float* w_fc2  = (const float*)d_in[2];
  const float* b_fc2  = (const float*)d_in[3];
  const float* alpha  = (const float*)d_in[4];
  const float* weight = (const float*)d_in[5];
  const float* bias_w = (const float*)d_in[6];

  float* out = (float*)d_out;
  float* raw_out = out + (size_t)32 * 256 * 56 * 56;  // tuple: (out, raw)

  char* ws = (char*)d_ws;
  __hip_bfloat16* Xpad = (__hip_bfloat16*)(ws + XPAD_OFF);
  __hip_bfloat16* Wq   = (__hip_bfloat16*)(ws + WQ_OFF);
  float* pooled        = (float*)(ws + POOL_OFF);
  int* idx             = (int*)(ws + IDX_OFF);

  // quant first: block 0 zeroes pooled (replaces memset dispatch; stream
  // order guarantees completion before padx's atomics).
  quant_kernel<<<256, 256, 0, stream>>>(weight, alpha, Wq, pooled);
  padx_kernel<<<dim3(29, 32), 512, 0, stream>>>(x, Xpad, pooled);
  fc_argmax_kernel<<<32, 128, 0, stream>>>(pooled, w_fc1, w_fc2, b_fc2, raw_out, idx);
  conv_kernel<<<dim3(32, 28), 256, 0, stream>>>(Xpad, Wq, idx, bias_w, out);
}

// Round 8
// 328.211 us; speedup vs baseline: 1.5607x; 1.5607x over previous
//
#include <hip/hip_runtime.h>
#include <hip/hip_bf16.h>

typedef __attribute__((ext_vector_type(8))) short short8;
typedef __attribute__((ext_vector_type(16))) float f32x16;

// ---------------- workspace layout (bytes) ----------------
// Xpad bf16 NHWC [32][58][58][256]                    : 55,115,776 B
// Wq   bf16 32x32-frag layout [4][2][9][8][...]       :  4,718,592 B
// pooled f32 [32][256] (SUMS, zeroed by quant blk 0)  :     32,768 B
// idx  int [32]                                       :        128 B
#define XPAD_OFF   0u
#define WQ_OFF     55115776u
#define POOL_OFF   59834368u
#define IDX_OFF    59867136u

__device__ __forceinline__ void gl_lds16(const void* g, void* l) {
  __builtin_amdgcn_global_load_lds(
      (const __attribute__((address_space(1))) unsigned int*)g,
      (__attribute__((address_space(3))) unsigned int*)l, 16, 0, 0);
}

// ---- 1. fc1/relu/fc2 + argmax: one block per sample ----
__global__ __launch_bounds__(128) void fc_argmax_kernel(
    const float* __restrict__ pooled, const float* __restrict__ w_fc1,
    const float* __restrict__ w_fc2, const float* __restrict__ b_fc2,
    float* __restrict__ raw_out, int* __restrict__ idx) {
  __shared__ float h[65];
  __shared__ float raws[4];
  const int b = blockIdx.x, t = threadIdx.x;
  if (t < 65) {
    float s = 0.f;
    const float4* pb = (const float4*)(pooled + b * 256);
    const float4* wr = (const float4*)(w_fc1 + t * 256);
    for (int c = 0; c < 64; ++c) {
      const float4 a4 = pb[c], b4 = wr[c];
      s += a4.x * b4.x + a4.y * b4.y + a4.z * b4.z + a4.w * b4.w;
    }
    s *= (1.0f / 3136.0f);
    h[t] = s > 0.f ? s : 0.f;
  }
  __syncthreads();
  if (t < 4) {
    float s = b_fc2[t];
    const float* wr = w_fc2 + t * 65;
    for (int j = 0; j < 65; ++j) s += h[j] * wr[j];
    raws[t] = s;
    raw_out[b * 4 + t] = s;
  }
  __syncthreads();
  if (t == 0) {
    int best = 0; float bv = raws[0];
    for (int k = 1; k < 4; ++k) if (raws[k] > bv) { bv = raws[k]; best = k; }
    idx[b] = best;
  }
}

// ---- 2. LSQ quantize + reorder, coalesced via LDS transpose ----
// (verified round 4; ~6-8us) 256 blocks, each owns (k, oc-tile 32, ch-tile 32,
// all 9 taps); coalesced float4 stage -> LDS [32][292] -> native-order short8
// stores. Output mapping matches conv's W0 indexing:
//   u = ((k*2+ot)*9+tap)*64 + cbh*8+wm*4+octile*2+s ; elem d = u*512+lane*8+cl
//   oc = ot*128+wm*64+octile*32+(lane&31), ch = cbh*32+s*16+(lane>>5)*8+cl.
// Block 0 also zeroes pooled (replaces the memset dispatch; quant runs first).
__global__ __launch_bounds__(256) void quant_kernel(
    const float* __restrict__ weight, const float* __restrict__ alpha,
    __hip_bfloat16* __restrict__ Wq, float* __restrict__ pooled) {
  __shared__ __attribute__((aligned(16))) float Ws[32 * 292];
  const int tid = threadIdx.x;
  const int B = blockIdx.x;
  if (B == 0) {
    for (int i = tid; i < 8192; i += 256) pooled[i] = 0.f;
  }
  const int cbh    = B & 7;
  const int octile = (B >> 3) & 1;
  const int wm     = (B >> 4) & 1;
  const int ot     = (B >> 5) & 1;
  const int k      = B >> 6;
  const int oc0 = ot * 128 + wm * 64 + octile * 32;

  // stage: oc row (tid>>3), quad (tid&7); 9 float4 per thread
  const int ocr = tid >> 3, q = tid & 7;
  const float4* src = (const float4*)weight +
                      (size_t)k * 147456 + (size_t)(oc0 + ocr) * 576 + cbh * 72;
  #pragma unroll
  for (int j = 0; j < 9; ++j) {
    const float4 v = src[q + 8 * j];
    *(float4*)&Ws[ocr * 292 + 4 * (q + 8 * j)] = v;
  }
  __syncthreads();

  // write: thread t = (p = t>>7 tap parity, s = (t>>6)&1, lane = t&63)
  const int p    = tid >> 7;
  const int s    = (tid >> 6) & 1;
  const int lane = tid & 63;
  const int ocl  = lane & 31;
  const int khl  = lane >> 5;
  const float a = alpha[k];
  const int ubase = ((k * 2 + ot) * 9) * 64 + (cbh * 8 + wm * 4 + octile * 2 + s);
  #pragma unroll
  for (int m = 0; m < 5; ++m) {
    const int tap = 2 * m + p;
    if (tap > 8) break;   // only (m=4, p=1)
    union { short8 v; __hip_bfloat16 e[8]; } uo;
    #pragma unroll
    for (int cl = 0; cl < 8; ++cl) {
      const int chl = s * 16 + khl * 8 + cl;
      float v = Ws[ocl * 292 + chl * 9 + tap] / a;
      if (oc0 == 0 && ocl == 0 && cbh == 0 && chl == 0 && tap == 0) {
        if (k == 0)      v = fminf(fmaxf(v, -2.f), 1.f);
        else if (k == 1) v = fminf(fmaxf(v, -4.f), 3.f);
        else if (k == 2) v = fminf(fmaxf(v, -8.f), 7.f);
      }
      uo.e[cl] = __float2bfloat16(rintf(v) * a);
    }
    const size_t u = (size_t)(ubase + tap * 64);
    *(short8*)&Wq[u * 512 + lane * 8] = uo.v;
  }
}

// ---- 3. pad + NCHW->NHWC + bf16 via LDS transpose, fused global-avg-pool ----
// (verified round 4 build, part of the 328.9us total) Xpad rows 58 (y'),
// cols 58 (x' = 0..57; input col x'-1), 256 ch. float4 global loads; LDS
// stride 133 (132 gave ~7-way write conflicts; 133 -> step 5, coprime-ish).
__global__ __launch_bounds__(256) void padx_kernel(const float* __restrict__ x,
                                                   __hip_bfloat16* __restrict__ Xpad,
                                                   float* __restrict__ pooled) {
  __shared__ float T[56 * 133];   // [px][c_local], stride 133
  const int yp = blockIdx.x;
  const int c0 = blockIdx.y * 128;
  const int b  = blockIdx.z;
  const int tid = threadIdx.x;
  __hip_bfloat16* orow = Xpad + ((size_t)(b * 58 + yp) * 58) * 256 + c0;
  const short8 zero8 = (short8){0, 0, 0, 0, 0, 0, 0, 0};
  const bool rowin = (yp >= 1 && yp <= 56);
  if (rowin) {
    const float4* xb4 = (const float4*)(x + (((size_t)b * 256 + c0) * 56 + (yp - 1)) * 56);
    for (int i = tid; i < 1792; i += 256) {             // 128ch x 14 float4
      const int cl = i / 14, p4 = i - cl * 14;
      const float4 v = xb4[(size_t)cl * 784 + p4];
      float* Tp = &T[(p4 * 4) * 133 + cl];
      Tp[0] = v.x; Tp[133] = v.y; Tp[266] = v.z; Tp[399] = v.w;
    }
    __syncthreads();
    if (tid < 128) {                                   // fused pooling
      float s = 0.f;
      for (int px = 0; px < 56; ++px) s += T[px * 133 + tid];
      atomicAdd(pooled + b * 256 + c0 + tid, s);
    }
    for (int i = tid; i < 896; i += 256) {             // data cols xp=1..56
      const int px = i >> 4, cg = (i & 15) * 8;
      union { short8 v; __hip_bfloat16 e[8]; } u;
      #pragma unroll
      for (int r = 0; r < 8; ++r) u.e[r] = __float2bfloat16(T[px * 133 + cg + r]);
      *(short8*)&orow[(px + 1) * 256 + cg] = u.v;
    }
    for (int i = tid; i < 32; i += 256) {              // pad cols xp=0,57
      const int cg = (i & 15) * 8;
      const int xp = (i >> 4) ? 57 : 0;
      *(short8*)&orow[xp * 256 + cg] = zero8;
    }
  } else {                                             // border rows y'=0,57
    for (int i = tid; i < 58 * 16; i += 256) {
      const int xp = i >> 4, cg = (i & 15) * 8;
      *(short8*)&orow[xp * 256 + cg] = zero8;
    }
  }
}

// ---- 4. conv as implicit GEMM, bf16 MFMA 32x32x16 ----
// v4 (VERIFIED 126.0us, MfmaUtil 45%, FETCH 64.5MB; total 328.9us): v1
// structure + XCD grid remap (b, pt*2+ot): linear%8 = b%8 pins all 28 blocks
// of sample b to one XCD; its 1.72MB Xpad slice is L2-resident and the
// ot-pair of each (b,pt) shares its 178KB X tile. Staging hits L2 (~200cy).
// POST-MORTEM LOG (5 structural deviations, all regressed — do not retry):
//  - launch_bounds(256,3): VGPR cap 170 < 128acc+~100 -> acc spill, 8.7x.
//  - ot-fused 512-thr block (v2): tight vmcnt + 448-block tail, -26%.
//  - wave retile 128oc x 64px (v2, v7): BOTH ~35% slower. Doubled W-load
//    issue per MFMA outweighs halved LDS reads/conflicts.
//  - s_setprio around compute (v8): -2.3x. Priority is per-WAVE; same wave
//    does staging+compute -> starves co-resident waves' staging and breaks
//    XCD L2 temporal locality (FETCH 64->216MB). T5 needs role-split waves.
// block 128oc x 256px (4 rows x 64 cols), 4 waves 2x2; wave tile 64oc x 128px
// = 2 octile x 4 pxtile of 32x32, acc 8 x f32x16 = 128 regs.
// K: 8 chunks of 32ch. X double-buffered in LDS, staging ISSUE SPREAD over
// taps 0..5 of the previous chunk (every vmcnt wait finds loads >=2 taps
// old). W: depth-2 register ring (3 sets x 4 granules) from fragment-ready
// global layout -> all waits have ~2000cyc drain distance.
__global__ __launch_bounds__(256, 2) void conv_kernel(
    const __hip_bfloat16* __restrict__ Xpad, const __hip_bfloat16* __restrict__ Wq,
    const int* __restrict__ idx, const float* __restrict__ bias_w,
    float* __restrict__ out) {
  // per buffer: 6 rows x 58 px x 4 granules = 1392 data granules; padded to
  // 1424 granules (22784 B) to absorb discarded-lane reads (col<=65) and the
  // staging tail. 2 buffers = 45568 B.
  __shared__ __attribute__((aligned(16))) __hip_bfloat16 Xs[22784];

  const int tid = threadIdx.x;
  const int lane = tid & 63;
  const int w = tid >> 6;
  const int wm = w & 1;          // oc-half (64)
  const int wn = w >> 1;         // px-half: rows {0,1} vs {2,3}

  const int b  = blockIdx.x;          // 0..31 -> XCD b%8
  const int pt = blockIdx.y >> 1;     // 0..13 -> output rows 4*pt..4*pt+3
  const int ot = blockIdx.y & 1;      // 0..1 (adjacent dispatch with its pair)
  const int Y0 = pt * 4;
  const int OC0 = ot * 128;
  const int kb = idx[b];

  const __hip_bfloat16* xb = Xpad + (size_t)b * (58 * 58 * 256);
  const short8* W0 = (const short8*)Wq + (size_t)(kb * 2 + ot) * 36864;

  f32x16 acc[2][4];
  #pragma unroll
  for (int i = 0; i < 2; ++i)
    #pragma unroll
    for (int j = 0; j < 4; ++j)
      acc[i][j] = (f32x16){0,0,0,0,0,0,0,0,0,0,0,0,0,0,0,0};

  const int nlo = lane & 31;     // oc%32 (A) / px col (B)
  const int khalf = lane >> 5;   // ch-half selector

  // one staging segment (64 granules) of chunk cbn into buffer bufsel
  auto stageseg = [&](int cbn, int bufsel, int k) {
    int sidx = k * 64 + lane;
    int p = sidx >> 2;
    if (p > 347) p = 347;                   // tail dups -> pad granules
    const int gsel = (sidx & 3) ^ ((p >> 1) & 3);
    const int r = p / 58, xc = p - r * 58;
    gl_lds16(xb + (((Y0 + r) * 58 + xc) * 256 + cbn * 32 + gsel * 8),
             (char*)Xs + bufsel * 22784 + k * 1024);
  };

  for (int k = w; k < 22; k += 4) stageseg(0, 0, k);   // chunk 0 burst
  __syncthreads();

  // W register ring, depth 2: afr[set][octile*2+s]
  short8 afr[3][4];
  #pragma unroll
  for (int oc2 = 0; oc2 < 2; ++oc2)
    #pragma unroll
    for (int s2 = 0; s2 < 2; ++s2) {
      afr[0][oc2 * 2 + s2] = W0[0 * 4096 + 0 * 512 + wm * 256 + oc2 * 128 + s2 * 64 + lane];
      afr[1][oc2 * 2 + s2] = W0[1 * 4096 + 0 * 512 + wm * 256 + oc2 * 128 + s2 * 64 + lane];
    }

  for (int cbh = 0; cbh < 8; ++cbh) {
    const __hip_bfloat16* cur = Xs + (cbh & 1) * 11392;
    const int nb = (cbh + 1) & 1;

    #pragma unroll
    for (int t = 0; t < 9; ++t) {
      const int dy = t / 3, dx = t - dy * 3;
      // spread X staging for next chunk: ~3-4 segs per tap, taps 0..5
      if (cbh < 7) {
        if (t < 5) stageseg(cbh + 1, nb, w + 4 * t);
        else if (t == 5 && w < 2) stageseg(cbh + 1, nb, w + 20);
      }
      // W prefetch for tt+2 (depth-2 ring)
      if (cbh < 7 || t < 7) {
        const int tap2 = (t + 2) % 9, cb2 = cbh + (t + 2) / 9;
        #pragma unroll
        for (int oc2 = 0; oc2 < 2; ++oc2)
          #pragma unroll
          for (int s2 = 0; s2 < 2; ++s2)
            afr[(t + 2) % 3][oc2 * 2 + s2] =
                W0[tap2 * 4096 + cb2 * 512 + wm * 256 + oc2 * 128 + s2 * 64 + lane];
      }
      // compute: 2 K16-steps x 4 px-tiles x 2 oc-tiles
      #pragma unroll
      for (int s = 0; s < 2; ++s) {
        #pragma unroll
        for (int j = 0; j < 4; ++j) {
          const int row = wn * 2 + (j >> 1) + dy;
          const int col = (j & 1) * 32 + nlo + dx;
          const int p = row * 58 + col;
          const int slot = p * 4 + ((s * 2 + khalf) ^ ((p >> 1) & 3));
          const short8 bfr = *(const short8*)&cur[slot * 8];
          #pragma unroll
          for (int i = 0; i < 2; ++i)
            acc[i][j] = __builtin_amdgcn_mfma_f32_32x32x16_bf16(
                afr[t % 3][i * 2 + s], bfr, acc[i][j], 0, 0, 0);
        }
      }
    }
    __syncthreads();   // staging of next chunk complete; cur readers done
  }

  // epilogue: 32x32 C/D: col=lane&31, row=(reg&3)+8*(reg>>2)+4*(lane>>5)
  const float* biasb = bias_w + kb * 256;
  #pragma unroll
  for (int i = 0; i < 2; ++i) {
    #pragma unroll
    for (int j = 0; j < 4; ++j) {
      const int xcol = (j & 1) * 32 + nlo;
      if (xcol < 56) {
        const int y = Y0 + wn * 2 + (j >> 1);
        #pragma unroll
        for (int reg = 0; reg < 16; ++reg) {
          const int row = (reg & 3) + 8 * (reg >> 2) + 4 * khalf;
          const int oc = OC0 + wm * 64 + i * 32 + row;
          out[(((size_t)b * 256 + oc) * 56 + y) * 56 + xcol] =
              acc[i][j][reg] + biasb[oc];
        }
      }
    }
  }
}

extern "C" void kernel_launch(void* const* d_in, const int* in_sizes, int n_in,
                              void* d_out, int out_size, void* d_ws, size_t ws_size,
                              hipStream_t stream) {
  const float* x      = (const float*)d_in[0];
  const float* w_fc1  = (const float*)d_in[1];
  const float* w_fc2  = (const float*)d_in[2];
  const float* b_fc2  = (const float*)d_in[3];
  const float* alpha  = (const float*)d_in[4];
  const float* weight = (const float*)d_in[5];
  const float* bias_w = (const float*)d_in[6];

  float* out = (float*)d_out;
  float* raw_out = out + (size_t)32 * 256 * 56 * 56;  // tuple: (out, raw)

  char* ws = (char*)d_ws;
  __hip_bfloat16* Xpad = (__hip_bfloat16*)(ws + XPAD_OFF);
  __hip_bfloat16* Wq   = (__hip_bfloat16*)(ws + WQ_OFF);
  float* pooled        = (float*)(ws + POOL_OFF);
  int* idx             = (int*)(ws + IDX_OFF);

  // quant first: block 0 zeroes pooled (replaces memset dispatch; stream
  // order guarantees completion before padx's atomics).
  quant_kernel<<<256, 256, 0, stream>>>(weight, alpha, Wq, pooled);
  padx_kernel<<<dim3(58, 2, 32), 256, 0, stream>>>(x, Xpad, pooled);
  fc_argmax_kernel<<<32, 128, 0, stream>>>(pooled, w_fc1, w_fc2, b_fc2, raw_out, idx);
  conv_kernel<<<dim3(32, 28), 256, 0, stream>>>(Xpad, Wq, idx, bias_w, out);
}

// Round 9
// 323.558 us; speedup vs baseline: 1.5832x; 1.0144x over previous
//
#include <hip/hip_runtime.h>
#include <hip/hip_bf16.h>

typedef __attribute__((ext_vector_type(8))) short short8;
typedef __attribute__((ext_vector_type(16))) float f32x16;

// ---------------- workspace layout (bytes) ----------------
// Xpad bf16 NHWC [32][58][58][256]                    : 55,115,776 B
// Wq   bf16 32x32-frag layout [4][2][9][8][...]       :  4,718,592 B
// pooled f32 [32][256] (SUMS, zeroed by memset)       :     32,768 B
// idx  int [32]                                       :        128 B
#define XPAD_OFF   0u
#define WQ_OFF     55115776u
#define POOL_OFF   59834368u
#define IDX_OFF    59867136u

__device__ __forceinline__ void gl_lds16(const void* g, void* l) {
  __builtin_amdgcn_global_load_lds(
      (const __attribute__((address_space(1))) unsigned int*)g,
      (__attribute__((address_space(3))) unsigned int*)l, 16, 0, 0);
}

// ---- 1. fc1/relu/fc2 + argmax: one block per sample ----
__global__ __launch_bounds__(128) void fc_argmax_kernel(
    const float* __restrict__ pooled, const float* __restrict__ w_fc1,
    const float* __restrict__ w_fc2, const float* __restrict__ b_fc2,
    float* __restrict__ raw_out, int* __restrict__ idx) {
  __shared__ float h[65];
  __shared__ float raws[4];
  const int b = blockIdx.x, t = threadIdx.x;
  if (t < 65) {
    float s = 0.f;
    const float4* pb = (const float4*)(pooled + b * 256);
    const float4* wr = (const float4*)(w_fc1 + t * 256);
    for (int c = 0; c < 64; ++c) {
      const float4 a4 = pb[c], b4 = wr[c];
      s += a4.x * b4.x + a4.y * b4.y + a4.z * b4.z + a4.w * b4.w;
    }
    s *= (1.0f / 3136.0f);
    h[t] = s > 0.f ? s : 0.f;
  }
  __syncthreads();
  if (t < 4) {
    float s = b_fc2[t];
    const float* wr = w_fc2 + t * 65;
    for (int j = 0; j < 65; ++j) s += h[j] * wr[j];
    raws[t] = s;
    raw_out[b * 4 + t] = s;
  }
  __syncthreads();
  if (t == 0) {
    int best = 0; float bv = raws[0];
    for (int k = 1; k < 4; ++k) if (raws[k] > bv) { bv = raws[k]; best = k; }
    idx[b] = best;
  }
}

// ---- 2+3 fused: quant (blocks 0..255) || padx (blocks 256..3967) ----
// Bodies are VERBATIM from the verified round-4/round-8 kernels (quant-v2
// coalesced LDS-transpose; padx-v2 float4 + stride-133). Fusion rationale:
// the two are fully independent (weight->Wq vs x->Xpad/pooled); running them
// in one dispatch overlaps quant (~6-8us) under memory-bound padx. quant
// blocks come FIRST in linear dispatch order so they start immediately.
// pooled zeroing is back in a hipMemsetAsync (stream-ordered before this
// dispatch -> padx atomics safe). LDS: shared 37376B arena (quant 32*292*4 =
// 37376; padx 56*133*4 = 29792).
__global__ __launch_bounds__(256) void quant_padx_kernel(
    const float* __restrict__ weight, const float* __restrict__ alpha,
    __hip_bfloat16* __restrict__ Wq, const float* __restrict__ x,
    __hip_bfloat16* __restrict__ Xpad, float* __restrict__ pooled) {
  __shared__ __attribute__((aligned(16))) char smem[37376];
  const int bid = blockIdx.x;
  const int tid = threadIdx.x;

  if (bid < 256) {
    // ---------------- quant body (B = bid) ----------------
    float* Ws = (float*)smem;                 // [32][292]
    const int B = bid;
    const int cbh    = B & 7;
    const int octile = (B >> 3) & 1;
    const int wm     = (B >> 4) & 1;
    const int ot     = (B >> 5) & 1;
    const int k      = B >> 6;
    const int oc0 = ot * 128 + wm * 64 + octile * 32;

    const int ocr = tid >> 3, q = tid & 7;
    const float4* src = (const float4*)weight +
                        (size_t)k * 147456 + (size_t)(oc0 + ocr) * 576 + cbh * 72;
    #pragma unroll
    for (int j = 0; j < 9; ++j) {
      const float4 v = src[q + 8 * j];
      *(float4*)&Ws[ocr * 292 + 4 * (q + 8 * j)] = v;
    }
    __syncthreads();

    const int p    = tid >> 7;
    const int s    = (tid >> 6) & 1;
    const int lane = tid & 63;
    const int ocl  = lane & 31;
    const int khl  = lane >> 5;
    const float a = alpha[k];
    const int ubase = ((k * 2 + ot) * 9) * 64 + (cbh * 8 + wm * 4 + octile * 2 + s);
    #pragma unroll
    for (int m = 0; m < 5; ++m) {
      const int tap = 2 * m + p;
      if (tap > 8) break;   // only (m=4, p=1)
      union { short8 v; __hip_bfloat16 e[8]; } uo;
      #pragma unroll
      for (int cl = 0; cl < 8; ++cl) {
        const int chl = s * 16 + khl * 8 + cl;
        float v = Ws[ocl * 292 + chl * 9 + tap] / a;
        if (oc0 == 0 && ocl == 0 && cbh == 0 && chl == 0 && tap == 0) {
          if (k == 0)      v = fminf(fmaxf(v, -2.f), 1.f);
          else if (k == 1) v = fminf(fmaxf(v, -4.f), 3.f);
          else if (k == 2) v = fminf(fmaxf(v, -8.f), 7.f);
        }
        uo.e[cl] = __float2bfloat16(rintf(v) * a);
      }
      const size_t u = (size_t)(ubase + tap * 64);
      *(short8*)&Wq[u * 512 + lane * 8] = uo.v;
    }
  } else {
    // ---------------- padx body ----------------
    // original grid (58, 2, 32): yp = x, c-half = y, b = z
    float* T = (float*)smem;                  // [px][c_local], stride 133
    const int lin = bid - 256;
    const int b   = lin / 116;
    const int rem = lin - b * 116;
    const int yp  = rem % 58;
    const int c0  = (rem / 58) * 128;
    __hip_bfloat16* orow = Xpad + ((size_t)(b * 58 + yp) * 58) * 256 + c0;
    const short8 zero8 = (short8){0, 0, 0, 0, 0, 0, 0, 0};
    const bool rowin = (yp >= 1 && yp <= 56);
    if (rowin) {
      const float4* xb4 = (const float4*)(x + (((size_t)b * 256 + c0) * 56 + (yp - 1)) * 56);
      for (int i = tid; i < 1792; i += 256) {             // 128ch x 14 float4
        const int cl = i / 14, p4 = i - cl * 14;
        const float4 v = xb4[(size_t)cl * 784 + p4];
        float* Tp = &T[(p4 * 4) * 133 + cl];
        Tp[0] = v.x; Tp[133] = v.y; Tp[266] = v.z; Tp[399] = v.w;
      }
      __syncthreads();
      if (tid < 128) {                                   // fused pooling
        float s = 0.f;
        for (int px = 0; px < 56; ++px) s += T[px * 133 + tid];
        atomicAdd(pooled + b * 256 + c0 + tid, s);
      }
      for (int i = tid; i < 896; i += 256) {             // data cols xp=1..56
        const int px = i >> 4, cg = (i & 15) * 8;
        union { short8 v; __hip_bfloat16 e[8]; } u;
        #pragma unroll
        for (int r = 0; r < 8; ++r) u.e[r] = __float2bfloat16(T[px * 133 + cg + r]);
        *(short8*)&orow[(px + 1) * 256 + cg] = u.v;
      }
      for (int i = tid; i < 32; i += 256) {              // pad cols xp=0,57
        const int cg = (i & 15) * 8;
        const int xp = (i >> 4) ? 57 : 0;
        *(short8*)&orow[xp * 256 + cg] = zero8;
      }
    } else {                                             // border rows y'=0,57
      for (int i = tid; i < 58 * 16; i += 256) {
        const int xp = i >> 4, cg = (i & 15) * 8;
        *(short8*)&orow[xp * 256 + cg] = zero8;
      }
    }
  }
}

// ---- 4. conv as implicit GEMM, bf16 MFMA 32x32x16 ----
// v4 (VERIFIED 126.0-127.0us across rounds 3/4/5/8; MfmaUtil 45%, FETCH
// 64.5MB): v1 structure + XCD grid remap (b, pt*2+ot): linear%8 = b%8 pins
// all 28 blocks of sample b to one XCD; its 1.72MB Xpad slice is L2-resident
// and the ot-pair of each (b,pt) shares its 178KB X tile.
// POST-MORTEM LOG (5 structural deviations, all regressed — do not retry):
//  - launch_bounds(256,3): VGPR cap 170 < 128acc+~100 -> acc spill, 8.7x.
//  - ot-fused 512-thr block (v2): tight vmcnt + 448-block tail, -26%.
//  - wave retile 128oc x 64px (v2, v7): BOTH ~35% slower. Doubled W-load
//    issue per MFMA outweighs halved LDS reads/conflicts.
//  - s_setprio around compute (v8): -2.3x. Priority is per-WAVE; same wave
//    does staging+compute -> starves co-resident waves' staging and breaks
//    XCD L2 temporal locality (FETCH 64->216MB). T5 needs role-split waves.
// block 128oc x 256px (4 rows x 64 cols), 4 waves 2x2; wave tile 64oc x 128px
// = 2 octile x 4 pxtile of 32x32, acc 8 x f32x16 = 128 regs.
// K: 8 chunks of 32ch. X double-buffered in LDS, staging ISSUE SPREAD over
// taps 0..5 of the previous chunk (every vmcnt wait finds loads >=2 taps
// old). W: depth-2 register ring (3 sets x 4 granules) from fragment-ready
// global layout -> all waits have ~2000cyc drain distance.
__global__ __launch_bounds__(256, 2) void conv_kernel(
    const __hip_bfloat16* __restrict__ Xpad, const __hip_bfloat16* __restrict__ Wq,
    const int* __restrict__ idx, const float* __restrict__ bias_w,
    float* __restrict__ out) {
  // per buffer: 6 rows x 58 px x 4 granules = 1392 data granules; padded to
  // 1424 granules (22784 B) to absorb discarded-lane reads (col<=65) and the
  // staging tail. 2 buffers = 45568 B.
  __shared__ __attribute__((aligned(16))) __hip_bfloat16 Xs[22784];

  const int tid = threadIdx.x;
  const int lane = tid & 63;
  const int w = tid >> 6;
  const int wm = w & 1;          // oc-half (64)
  const int wn = w >> 1;         // px-half: rows {0,1} vs {2,3}

  const int b  = blockIdx.x;          // 0..31 -> XCD b%8
  const int pt = blockIdx.y >> 1;     // 0..13 -> output rows 4*pt..4*pt+3
  const int ot = blockIdx.y & 1;      // 0..1 (adjacent dispatch with its pair)
  const int Y0 = pt * 4;
  const int OC0 = ot * 128;
  const int kb = idx[b];

  const __hip_bfloat16* xb = Xpad + (size_t)b * (58 * 58 * 256);
  const short8* W0 = (const short8*)Wq + (size_t)(kb * 2 + ot) * 36864;

  f32x16 acc[2][4];
  #pragma unroll
  for (int i = 0; i < 2; ++i)
    #pragma unroll
    for (int j = 0; j < 4; ++j)
      acc[i][j] = (f32x16){0,0,0,0,0,0,0,0,0,0,0,0,0,0,0,0};

  const int nlo = lane & 31;     // oc%32 (A) / px col (B)
  const int khalf = lane >> 5;   // ch-half selector

  // one staging segment (64 granules) of chunk cbn into buffer bufsel
  auto stageseg = [&](int cbn, int bufsel, int k) {
    int sidx = k * 64 + lane;
    int p = sidx >> 2;
    if (p > 347) p = 347;                   // tail dups -> pad granules
    const int gsel = (sidx & 3) ^ ((p >> 1) & 3);
    const int r = p / 58, xc = p - r * 58;
    gl_lds16(xb + (((Y0 + r) * 58 + xc) * 256 + cbn * 32 + gsel * 8),
             (char*)Xs + bufsel * 22784 + k * 1024);
  };

  for (int k = w; k < 22; k += 4) stageseg(0, 0, k);   // chunk 0 burst
  __syncthreads();

  // W register ring, depth 2: afr[set][octile*2+s]
  short8 afr[3][4];
  #pragma unroll
  for (int oc2 = 0; oc2 < 2; ++oc2)
    #pragma unroll
    for (int s2 = 0; s2 < 2; ++s2) {
      afr[0][oc2 * 2 + s2] = W0[0 * 4096 + 0 * 512 + wm * 256 + oc2 * 128 + s2 * 64 + lane];
      afr[1][oc2 * 2 + s2] = W0[1 * 4096 + 0 * 512 + wm * 256 + oc2 * 128 + s2 * 64 + lane];
    }

  for (int cbh = 0; cbh < 8; ++cbh) {
    const __hip_bfloat16* cur = Xs + (cbh & 1) * 11392;
    const int nb = (cbh + 1) & 1;

    #pragma unroll
    for (int t = 0; t < 9; ++t) {
      const int dy = t / 3, dx = t - dy * 3;
      // spread X staging for next chunk: ~3-4 segs per tap, taps 0..5
      if (cbh < 7) {
        if (t < 5) stageseg(cbh + 1, nb, w + 4 * t);
        else if (t == 5 && w < 2) stageseg(cbh + 1, nb, w + 20);
      }
      // W prefetch for tt+2 (depth-2 ring)
      if (cbh < 7 || t < 7) {
        const int tap2 = (t + 2) % 9, cb2 = cbh + (t + 2) / 9;
        #pragma unroll
        for (int oc2 = 0; oc2 < 2; ++oc2)
          #pragma unroll
          for (int s2 = 0; s2 < 2; ++s2)
            afr[(t + 2) % 3][oc2 * 2 + s2] =
                W0[tap2 * 4096 + cb2 * 512 + wm * 256 + oc2 * 128 + s2 * 64 + lane];
      }
      // compute: 2 K16-steps x 4 px-tiles x 2 oc-tiles
      #pragma unroll
      for (int s = 0; s < 2; ++s) {
        #pragma unroll
        for (int j = 0; j < 4; ++j) {
          const int row = wn * 2 + (j >> 1) + dy;
          const int col = (j & 1) * 32 + nlo + dx;
          const int p = row * 58 + col;
          const int slot = p * 4 + ((s * 2 + khalf) ^ ((p >> 1) & 3));
          const short8 bfr = *(const short8*)&cur[slot * 8];
          #pragma unroll
          for (int i = 0; i < 2; ++i)
            acc[i][j] = __builtin_amdgcn_mfma_f32_32x32x16_bf16(
                afr[t % 3][i * 2 + s], bfr, acc[i][j], 0, 0, 0);
        }
      }
    }
    __syncthreads();   // staging of next chunk complete; cur readers done
  }

  // epilogue: 32x32 C/D: col=lane&31, row=(reg&3)+8*(reg>>2)+4*(lane>>5)
  const float* biasb = bias_w + kb * 256;
  #pragma unroll
  for (int i = 0; i < 2; ++i) {
    #pragma unroll
    for (int j = 0; j < 4; ++j) {
      const int xcol = (j & 1) * 32 + nlo;
      if (xcol < 56) {
        const int y = Y0 + wn * 2 + (j >> 1);
        #pragma unroll
        for (int reg = 0; reg < 16; ++reg) {
          const int row = (reg & 3) + 8 * (reg >> 2) + 4 * khalf;
          const int oc = OC0 + wm * 64 + i * 32 + row;
          out[(((size_t)b * 256 + oc) * 56 + y) * 56 + xcol] =
              acc[i][j][reg] + biasb[oc];
        }
      }
    }
  }
}

extern "C" void kernel_launch(void* const* d_in, const int* in_sizes, int n_in,
                              void* d_out, int out_size, void* d_ws, size_t ws_size,
                              hipStream_t stream) {
  const float* x      = (const float*)d_in[0];
  const float* w_fc1  = (const float*)d_in[1];
  const float* w_fc2  = (const float*)d_in[2];
  const float* b_fc2  = (const float*)d_in[3];
  const float* alpha  = (const float*)d_in[4];
  const float* weight = (const float*)d_in[5];
  const float* bias_w = (const float*)d_in[6];

  float* out = (float*)d_out;
  float* raw_out = out + (size_t)32 * 256 * 56 * 56;  // tuple: (out, raw)

  char* ws = (char*)d_ws;
  __hip_bfloat16* Xpad = (__hip_bfloat16*)(ws + XPAD_OFF);
  __hip_bfloat16* Wq   = (__hip_bfloat16*)(ws + WQ_OFF);
  float* pooled        = (float*)(ws + POOL_OFF);
  int* idx             = (int*)(ws + IDX_OFF);

  // memset completes before quant_padx in stream order -> padx atomics safe.
  hipMemsetAsync(pooled, 0, 32 * 256 * sizeof(float), stream);
  quant_padx_kernel<<<3968, 256, 0, stream>>>(weight, alpha, Wq, x, Xpad, pooled);
  fc_argmax_kernel<<<32, 128, 0, stream>>>(pooled, w_fc1, w_fc2, b_fc2, raw_out, idx);
  conv_kernel<<<dim3(32, 28), 256, 0, stream>>>(Xpad, Wq, idx, bias_w, out);
}